// Round 5
// baseline (179.710 us; speedup 1.0000x reference)
//
#include <hip/hip_runtime.h>
#include <hip/hip_fp16.h>
#include <math.h>

#define DIM 128

typedef _Float16 half8 __attribute__((ext_vector_type(8)));
typedef _Float16 half2v __attribute__((ext_vector_type(2)));
typedef float floatx4 __attribute__((ext_vector_type(4)));

// ---------------------------------------------------------------------------
// MFMA precompute (single dispatch, 128 rows/block, 256 thr = 4 waves):
//   blocks [0,nHB)        : H  = h          @ W1[  0:128]            -> fp16
//   blocks [nHB,+nRB)     : R' = rel_table  @ W1[128:256] + c0       -> fp16
//                            (c0 = rel_table[q] @ W1[256:384] + b1, folded)
//   blocks [nHB+nRB,...)  : T  = time_table @ W1[384:512]            -> fp16
// W1 block staged in LDS pre-swizzled to B-fragment order (ds_read_b128,
// conflict-free), float4 staging loads. Each wave computes 32 rows as two
// 16-row m-tiles sharing each B-fragment. mfma_f32_16x16x32_f16.
// ---------------------------------------------------------------------------
__global__ __launch_bounds__(256) void precompute(
    const float* __restrict__ h, const float* __restrict__ rel,
    const float* __restrict__ tim, const int* __restrict__ qrel,
    const float* __restrict__ W1, const float* __restrict__ b1,
    __half* __restrict__ Hh, __half* __restrict__ Rh, __half* __restrict__ Th,
    int n_nodes, int n_rels, int n_times, int nHB, int nRB)
{
    const int tid = threadIdx.x;
    const int b = blockIdx.x;

    const float* A; __half* Out; int M, k0, row0; bool isR = false;
    if (b < nHB)            { A = h;   Out = Hh; M = n_nodes; k0 = 0;   row0 = b * 128; }
    else if (b < nHB + nRB) { A = rel; Out = Rh; M = n_rels;  k0 = 128; row0 = (b - nHB) * 128; isR = true; }
    else                    { A = tim; Out = Th; M = n_times; k0 = 384; row0 = (b - nHB - nRB) * 128; }

    __shared__ _Float16 fragB[32 * 64 * 8];  // 32 KB: [ct*4+kc][lane][j]
    __shared__ float c0f[DIM];

    // Stage W1 block into B-fragment layout: B[k][n], n=lane&15, k=(lane>>4)*8+j
    // float4 loads (coalesced), scalar LDS scatter.
    for (int idx4 = tid; idx4 < DIM * DIM / 4; idx4 += 256) {
        const int k = idx4 >> 5;          // 32 float4 per W1 row
        const int n0 = (idx4 & 31) * 4;
        const float4 v = *(const float4*)&W1[(size_t)(k0 + k) * DIM + n0];
        const int kc = k >> 5, kr = k & 31, q = kr >> 3, j = kr & 7;
        const float vv[4] = {v.x, v.y, v.z, v.w};
#pragma unroll
        for (int i = 0; i < 4; ++i) {
            const int n = n0 + i, ct = n >> 4, n15 = n & 15;
            fragB[(((ct * 4 + kc) * 64) + (q * 16 + n15)) * 8 + j] = (_Float16)vv[i];
        }
    }
    if (isR && tid < DIM) {  // c0[n] = b1[n] + rel[q] @ W1[256:384]
        const int q = qrel[0];
        const float* hq = rel + (size_t)q * DIM;
        float s = b1[tid];
        for (int k = 0; k < DIM; ++k)
            s = fmaf(hq[k], W1[(size_t)(256 + k) * DIM + tid], s);
        c0f[tid] = s;
    }
    __syncthreads();

    const int w = tid >> 6;          // wave 0..3 -> rows [row0+w*32, +32)
    const int lane = tid & 63;
    const int m15 = lane & 15, q = lane >> 4;

    const float* aBase[2];
#pragma unroll
    for (int mt = 0; mt < 2; ++mt) {
        int arow = row0 + w * 32 + mt * 16 + m15;
        if (arow >= M) arow = M - 1;     // clamp (stores guarded below)
        aBase[mt] = A + (size_t)arow * DIM + q * 8;
    }

    floatx4 acc[2][8];
#pragma unroll
    for (int mt = 0; mt < 2; ++mt)
#pragma unroll
        for (int ct = 0; ct < 8; ++ct) acc[mt][ct] = (floatx4)0.f;

#pragma unroll
    for (int kc = 0; kc < 4; ++kc) {
        half8 af[2];
#pragma unroll
        for (int mt = 0; mt < 2; ++mt) {
            const float4 a0 = *(const float4*)(aBase[mt] + kc * 32);
            const float4 a1 = *(const float4*)(aBase[mt] + kc * 32 + 4);
            af[mt][0] = (_Float16)a0.x; af[mt][1] = (_Float16)a0.y;
            af[mt][2] = (_Float16)a0.z; af[mt][3] = (_Float16)a0.w;
            af[mt][4] = (_Float16)a1.x; af[mt][5] = (_Float16)a1.y;
            af[mt][6] = (_Float16)a1.z; af[mt][7] = (_Float16)a1.w;
        }
#pragma unroll
        for (int ct = 0; ct < 8; ++ct) {
            const half8 bf = *(half8*)&fragB[(((ct * 4 + kc) * 64) + lane) * 8];
            acc[0][ct] = __builtin_amdgcn_mfma_f32_16x16x32_f16(af[0], bf, acc[0][ct], 0, 0, 0);
            acc[1][ct] = __builtin_amdgcn_mfma_f32_16x16x32_f16(af[1], bf, acc[1][ct], 0, 0, 0);
        }
    }

    // C/D layout: col = lane&15, row = (lane>>4)*4 + reg  [m89-verified]
#pragma unroll
    for (int mt = 0; mt < 2; ++mt)
#pragma unroll
        for (int ct = 0; ct < 8; ++ct) {
            const int col = ct * 16 + m15;
            const float cadd = isR ? c0f[col] : 0.f;
#pragma unroll
            for (int r = 0; r < 4; ++r) {
                const int m = row0 + w * 32 + mt * 16 + q * 4 + r;
                if (m < M)
                    Out[(size_t)m * DIM + col] = (_Float16)(acc[mt][ct][r] + cadd);
            }
        }
}

// ---------------------------------------------------------------------------
// Edge kernel: persistent grid-stride; 16 lanes/group, 4 edges/iter with 12
// row-gathers in flight + next-iteration index prefetch. c0 folded into R.
// Packed fp16 adds/relu + v_dot2_f32_f16.
// out[e] = sigmoid(dot(relu(H[src]+R'[type]+T[time]), W2) + b2)
// ---------------------------------------------------------------------------
__device__ __forceinline__ float edot(uint4 hu, uint4 ru, uint4 tu,
                                      const half2v* __restrict__ w2h) {
    union U { uint4 u; half2v h[4]; };
    U H, R, T; H.u = hu; R.u = ru; T.u = tu;
    const half2v z = (half2v)(_Float16)0.f;
    float p = 0.f;
#pragma unroll
    for (int j = 0; j < 4; ++j) {
        half2v s = H.h[j] + R.h[j] + T.h[j];           // v_pk_add_f16 x2
        s = __builtin_elementwise_max(s, z);           // v_pk_max_f16
#if __has_builtin(__builtin_amdgcn_fdot2)
        p = __builtin_amdgcn_fdot2(s, w2h[j], p, false);  // v_dot2_f32_f16
#else
        p = fmaf((float)s[0], (float)w2h[j][0], p);
        p = fmaf((float)s[1], (float)w2h[j][1], p);
#endif
    }
    return p;
}

__global__ __launch_bounds__(256) void edge_kernel(
    const int* __restrict__ ei, const int* __restrict__ ety,
    const int* __restrict__ eti,
    const __half* __restrict__ Hh, const __half* __restrict__ Rh,
    const __half* __restrict__ Th,
    const float* __restrict__ W2, const float* __restrict__ b2,
    float* __restrict__ out, int E, int nGrpTotal)
{
    const int tid = threadIdx.x;
    const int l = tid & 15;
    int g = blockIdx.x * 16 + (tid >> 4);
    const int nQuad = (E + 3) >> 2;
    if (g >= nQuad) return;

    const float4 wA = ((const float4*)W2)[2 * l];
    const float4 wB = ((const float4*)W2)[2 * l + 1];
    half2v w2h[4];
    w2h[0][0] = (_Float16)wA.x; w2h[0][1] = (_Float16)wA.y;
    w2h[1][0] = (_Float16)wA.z; w2h[1][1] = (_Float16)wA.w;
    w2h[2][0] = (_Float16)wB.x; w2h[2][1] = (_Float16)wB.y;
    w2h[3][0] = (_Float16)wB.z; w2h[3][1] = (_Float16)wB.w;
    const float b2v = b2[0];

    int s[4], r[4], t[4];
#pragma unroll
    for (int i = 0; i < 4; ++i) {
        const int e = min(4 * g + i, E - 1);
        s[i] = ei[e]; r[i] = ety[e]; t[i] = eti[e];
    }

    while (true) {
        const int gn = g + nGrpTotal;
        // 12 gathers in flight
        uint4 hv[4], rv[4], tv[4];
#pragma unroll
        for (int i = 0; i < 4; ++i) {
            hv[i] = ((const uint4*)(Hh + (size_t)s[i] * DIM))[l];
            rv[i] = ((const uint4*)(Rh + (size_t)r[i] * DIM))[l];
            tv[i] = ((const uint4*)(Th + (size_t)t[i] * DIM))[l];
        }
        if (gn < nQuad) {  // prefetch next indices while gathers land
#pragma unroll
            for (int i = 0; i < 4; ++i) {
                const int e = min(4 * gn + i, E - 1);
                s[i] = ei[e]; r[i] = ety[e]; t[i] = eti[e];
            }
        }
        float p[4];
#pragma unroll
        for (int i = 0; i < 4; ++i)
            p[i] = edot(hv[i], rv[i], tv[i], w2h);
#pragma unroll
        for (int off = 8; off > 0; off >>= 1) {
#pragma unroll
            for (int i = 0; i < 4; ++i)
                p[i] += __shfl_down(p[i], off, 16);
        }
        if (l == 0) {
            const int e0 = 4 * g;
            float4 o;
            o.x = 1.f / (1.f + __expf(-(p[0] + b2v)));
            o.y = 1.f / (1.f + __expf(-(p[1] + b2v)));
            o.z = 1.f / (1.f + __expf(-(p[2] + b2v)));
            o.w = 1.f / (1.f + __expf(-(p[3] + b2v)));
            if (e0 + 3 < E) {
                *(float4*)(out + e0) = o;
            } else {
                const float ov[4] = {o.x, o.y, o.z, o.w};
                for (int i = 0; i < 4 && e0 + i < E; ++i) out[e0 + i] = ov[i];
            }
        }
        if (gn >= nQuad) break;
        g = gn;
    }
}

extern "C" void kernel_launch(void* const* d_in, const int* in_sizes, int n_in,
                              void* d_out, int out_size, void* d_ws, size_t ws_size,
                              hipStream_t stream) {
    const float* h          = (const float*)d_in[0];
    const int*   edge_index = (const int*)d_in[1];   // [2,E] flat; row 0 = src
    const int*   edge_type  = (const int*)d_in[2];
    const int*   edge_time  = (const int*)d_in[3];
    const int*   query_rel  = (const int*)d_in[4];
    const float* rel_table  = (const float*)d_in[5];
    const float* time_table = (const float*)d_in[6];
    const float* W1         = (const float*)d_in[7]; // [512,128] row-major
    const float* b1         = (const float*)d_in[8];
    const float* W2         = (const float*)d_in[9]; // [128,1]
    const float* b2         = (const float*)d_in[10];
    float* out = (float*)d_out;

    const int n_nodes = in_sizes[0] / DIM;
    const int E       = in_sizes[2];
    const int n_rels  = in_sizes[5] / DIM;
    const int n_times = in_sizes[6] / DIM;

    __half* Hh = (__half*)d_ws;
    __half* Rh = Hh + (size_t)n_nodes * DIM;
    __half* Th = Rh + (size_t)n_rels * DIM;

    const int nHB = (n_nodes + 127) / 128;
    const int nRB = (n_rels + 127) / 128;
    const int nTB = (n_times + 127) / 128;

    precompute<<<nHB + nRB + nTB, 256, 0, stream>>>(
        h, rel_table, time_table, query_rel, W1, b1,
        Hh, Rh, Th, n_nodes, n_rels, n_times, nHB, nRB);

    const int nBlk = 2048;  // persistent grid-stride
    edge_kernel<<<nBlk, 256, 0, stream>>>(
        edge_index, edge_type, edge_time, Hh, Rh, Th, W2, b2,
        out, E, nBlk * 16);
}